// Round 2
// baseline (762.028 us; speedup 1.0000x reference)
//
#include <hip/hip_runtime.h>
#include <math.h>

#define BATCH 65536
#define LEAD  24
#define MEM   51
#define NPRED 6
#define HID   128
#define DIN   54      // 2*LEAD + NPRED
#define TB    64      // batch elements per block
#define NBLK  4
#define NKNOT 5
#define OUTC  960     // LEAD * NBLK * 2 * NKNOT

__device__ __forceinline__ float sp_softplus(float z) {
    // jax.nn.softplus = max(z,0) + log1p(exp(-|z|))  (overflow-safe)
    return fmaxf(z, 0.0f) + log1pf(expf(-fabsf(z)));
}
__device__ __forceinline__ float silu_f(float z) {
    return z / (1.0f + expf(-z));
}

__global__ __launch_bounds__(256, 2) void fused_pdf_kernel(
    const float* __restrict__ x, const float* __restrict__ p, const float* __restrict__ f,
    const float* __restrict__ W_in, const float* __restrict__ b_in,
    const float* __restrict__ Ws0, const float* __restrict__ bs0,
    const float* __restrict__ Ws1, const float* __restrict__ bs1,
    const float* __restrict__ Ws2, const float* __restrict__ bs2,
    const float* __restrict__ Ws3, const float* __restrict__ bs3,
    const float* __restrict__ W_out, const float* __restrict__ b_out,
    float* __restrict__ out)
{
    __shared__ float s_in[DIN * TB];   // [k][b] transposed input tile
    __shared__ float s_h[HID * TB];    // [k][b] hidden tile

    const int t    = threadIdx.x;
    const int lane = t & 63;           // = local batch element in GEMM phases
    const int w    = t >> 6;           // wave id 0..3
    const int b0   = blockIdx.x * TB;

    // ---------------- phase 0: per-(b,lead) mean/std over 51 members ----------------
    {
        const int grp = lane >> 4, sub = lane & 15;
        for (int it = 0; it < (TB * LEAD) / 16; ++it) {
            int rowl = it * 16 + w * 4 + grp;               // 0..1535
            const float* xr = x + (size_t)(b0 * LEAD + rowl) * MEM;
            float v0 = xr[sub], v1 = xr[sub + 16], v2 = xr[sub + 32];
            float v3 = (sub < 3) ? xr[sub + 48] : 0.0f;
            float sum = v0 + v1 + v2 + v3;
            float ss  = v0 * v0 + v1 * v1 + v2 * v2 + v3 * v3;
            sum += __shfl_xor(sum, 1);  ss += __shfl_xor(ss, 1);
            sum += __shfl_xor(sum, 2);  ss += __shfl_xor(ss, 2);
            sum += __shfl_xor(sum, 4);  ss += __shfl_xor(ss, 4);
            sum += __shfl_xor(sum, 8);  ss += __shfl_xor(ss, 8);
            if (sub == 0) {
                int bl = rowl / LEAD, ld = rowl - bl * LEAD;
                float m   = sum / 51.0f;
                float var = (ss - 51.0f * m * m) / 50.0f;   // ddof=1
                s_in[(2 * ld) * TB + bl]     = m;
                s_in[(2 * ld + 1) * TB + bl] = sqrtf(fmaxf(var, 0.0f));
            }
        }
        for (int idx = t; idx < TB * NPRED; idx += 256) {
            int bl = idx / NPRED, j = idx - bl * NPRED;
            s_in[(2 * LEAD + j) * TB + bl] = p[(size_t)(b0 + bl) * NPRED + j];
        }
    }
    __syncthreads();

    // j-quarter owned by this wave; readfirstlane => provably wave-uniform => s_load path
    const int j0 = __builtin_amdgcn_readfirstlane(w * 32);

    float hreg[32];

    // ---------------- phase 1: input layer [54 -> 128], silu ----------------
    {
        float acc[32];
        #pragma unroll
        for (int jj = 0; jj < 32; ++jj) acc[jj] = 0.0f;
        for (int k = 0; k < DIN; ++k) {
            float a = s_in[k * TB + lane];
            const float* wr = W_in + k * HID + j0;
            #pragma unroll
            for (int jj = 0; jj < 32; ++jj) acc[jj] = fmaf(a, wr[jj], acc[jj]);
        }
        #pragma unroll
        for (int jj = 0; jj < 32; ++jj) {
            hreg[jj] = silu_f(acc[jj] + b_in[j0 + jj]);
            s_h[(j0 + jj) * TB + lane] = hreg[jj];
        }
    }
    __syncthreads();

    // ---------------- phase 2: 4 skip blocks: h = silu(h@W+b) + h ----------------
    const float* Wl[4] = {Ws0, Ws1, Ws2, Ws3};
    const float* Bl[4] = {bs0, bs1, bs2, bs3};
    #pragma unroll
    for (int L = 0; L < 4; ++L) {
        const float* Wp = Wl[L];
        const float* bp = Bl[L];
        float acc[32];
        #pragma unroll
        for (int jj = 0; jj < 32; ++jj) acc[jj] = 0.0f;
        for (int k = 0; k < HID; ++k) {
            float a = s_h[k * TB + lane];
            const float* wr = Wp + k * HID + j0;
            #pragma unroll
            for (int jj = 0; jj < 32; ++jj) acc[jj] = fmaf(a, wr[jj], acc[jj]);
        }
        __syncthreads();   // all reads of s_h complete before in-place overwrite
        #pragma unroll
        for (int jj = 0; jj < 32; ++jj) {
            hreg[jj] = silu_f(acc[jj] + bp[j0 + jj]) + hreg[jj];
            s_h[(j0 + jj) * TB + lane] = hreg[jj];
        }
        __syncthreads();
    }

    // ---------------- phase 3+4: output cols per lead + spline flow ----------------
    for (int q = 0; q < LEAD / 4; ++q) {
        const int lead = __builtin_amdgcn_readfirstlane(q * 4 + w);
        const int base = lead * 40;

        float acc[40];
        #pragma unroll
        for (int c = 0; c < 40; ++c) acc[c] = 0.0f;
        for (int k = 0; k < HID; ++k) {
            float a = s_h[k * TB + lane];
            const float* wr = W_out + k * OUTC + base;
            #pragma unroll
            for (int c = 0; c < 40; ++c) acc[c] = fmaf(a, wr[c], acc[c]);
        }
        #pragma unroll
        for (int c = 0; c < 40; ++c) acc[c] += b_out[base + c];

        float ff = f[(size_t)(b0 + lane) * LEAD + lead];
        float dt_prod = 1.0f;

        #pragma unroll
        for (int blk = 0; blk < NBLK; ++blk) {
            // knots: cumsum of [prm0, 0.001+softplus(prm1..4)]
            float tk[5], yk[5];
            tk[0] = acc[blk * 10 + 0];
            yk[0] = acc[blk * 10 + 5];
            #pragma unroll
            for (int kk = 1; kk < 5; ++kk) {
                tk[kk] = tk[kk - 1] + 0.001f + sp_softplus(acc[blk * 10 + kk]);
                yk[kk] = yk[kk - 1] + 0.001f + sp_softplus(acc[blk * 10 + 5 + kk]);
            }
            // monotone derivative estimates
            float df[4];
            #pragma unroll
            for (int j = 0; j < 4; ++j) df[j] = (yk[j + 1] - yk[j]) / (tk[j + 1] - tk[j]);
            float g02 = (yk[2] - yk[0]) / (tk[2] - tk[0]);
            float g13 = (yk[3] - yk[1]) / (tk[3] - tk[1]);
            float g24 = (yk[4] - yk[2]) / (tk[4] - tk[2]);
            float dd[5];
            dd[0] = df[0] * df[0] / g02;
            dd[1] = df[0] * df[1] / g02;
            dd[2] = df[1] * df[2] / g13;
            dd[3] = df[2] * df[3] / g24;
            dd[4] = df[3] * df[3] / g24;

            // bracket (searchsorted by comparison count)
            int cnt = (ff > tk[0]) + (ff > tk[1]) + (ff > tk[2]) + (ff > tk[3]) + (ff > tk[4]);
            bool e0 = (cnt == 0), e1 = (cnt == 5);
            int k0 = cnt - 1; k0 = k0 < 0 ? 0 : (k0 > 3 ? 3 : k0);

            float t0v = tk[0], t1v = tk[1], y0v = yk[0], y1v = yk[1], d0v = dd[0], d1v = dd[1];
            #pragma unroll
            for (int j = 1; j < 4; ++j) {
                bool c = (k0 == j);
                t0v = c ? tk[j] : t0v;  t1v = c ? tk[j + 1] : t1v;
                y0v = c ? yk[j] : y0v;  y1v = c ? yk[j + 1] : y1v;
                d0v = c ? dd[j] : d0v;  d1v = c ? dd[j + 1] : d1v;
            }

            float dt_ = t1v - t0v, dy_ = y1v - y0v;
            float s_  = dy_ / dt_;
            float e   = (ff - t0v) / dt_;
            float one_e = 1.0f - e;
            float bb  = d1v + d0v - 2.0f * s_;
            float n0  = dy_ * (s_ * e * e + d0v * e * one_e);
            float n1  = s_ + bb * e * one_e;
            float p_mid = y0v + n0 / n1;
            float p_lo  = d0v * ff + (y0v - d0v * t0v);
            float p_hi  = d1v * ff + (y1v - d1v * t1v);
            float val = e0 ? p_lo : (e1 ? p_hi : p_mid);

            float div0 = s_ * s_ * (d1v * e * e + 2.0f * s_ * e * one_e + d0v * one_e * one_e);
            float div1 = n1 * n1;
            float der  = e0 ? d0v : (e1 ? d1v : div0 / div1);

            dt_prod *= der;
            ff = val;
        }

        out[(size_t)(b0 + lane) * LEAD + lead] =
            expf(-0.5f * ff * ff) * dt_prod / 2.5066282746310002f;
    }
}

extern "C" void kernel_launch(void* const* d_in, const int* in_sizes, int n_in,
                              void* d_out, int out_size, void* d_ws, size_t ws_size,
                              hipStream_t stream) {
    const float* x     = (const float*)d_in[0];
    const float* p     = (const float*)d_in[1];
    const float* f     = (const float*)d_in[2];
    const float* W_in  = (const float*)d_in[3];
    const float* b_in  = (const float*)d_in[4];
    const float* Ws0   = (const float*)d_in[5];
    const float* bs0   = (const float*)d_in[6];
    const float* Ws1   = (const float*)d_in[7];
    const float* bs1   = (const float*)d_in[8];
    const float* Ws2   = (const float*)d_in[9];
    const float* bs2   = (const float*)d_in[10];
    const float* Ws3   = (const float*)d_in[11];
    const float* bs3   = (const float*)d_in[12];
    const float* W_out = (const float*)d_in[13];
    const float* b_out = (const float*)d_in[14];
    float* out = (float*)d_out;

    dim3 grid(BATCH / TB), block(256);
    fused_pdf_kernel<<<grid, block, 0, stream>>>(
        x, p, f, W_in, b_in, Ws0, bs0, Ws1, bs1, Ws2, bs2, Ws3, bs3, W_out, b_out, out);
}